// Round 1
// baseline (2248.912 us; speedup 1.0000x reference)
//
#include <hip/hip_runtime.h>
#include <stdint.h>

// Problem constants
#define NBATCH 16
#define NNODE  20
#define TSTEPS 63      // T-1
#define NEDGE  380
#define HID    256
#define G4     1024    // 4*HID

typedef __bf16 bf16x8 __attribute__((ext_vector_type(8)));
typedef float  f32x4  __attribute__((ext_vector_type(4)));

__device__ __forceinline__ float bf2f(unsigned short u){
  union { unsigned int i; float f; } v; v.i = ((unsigned int)u) << 16; return v.f;
}
__device__ __forceinline__ unsigned short f2bf(float f){
  union { float f; unsigned int i; } v; v.f = f;
  return (unsigned short)((v.i + 0x7FFFu + ((v.i >> 16) & 1u)) >> 16);
}
__device__ __forceinline__ bf16x8 as_frag(uint4 v){
  union { uint4 u; bf16x8 b; } c; c.u = v; return c.b;
}
__device__ __forceinline__ float sigmf(float x){ return 1.0f/(1.0f+__expf(-x)); }
__device__ __forceinline__ float tanh_f(float x){ float e=__expf(2.0f*x); return (e-1.0f)/(e+1.0f); }

// ---------------------------------------------------------------------------
// prep_a: combined weights (fp32): Wse=We[0:256]@Wei, Wre=We[256:512]@Wei,
//         Wcm=Wm@Wmi [4,1024], bcm=bm@Wmi+bmi+bmh, bce=be@Wei+bei+beh
// grid 2072 x 256
__global__ __launch_bounds__(256) void prep_a(
    const float* __restrict__ We, const float* __restrict__ Wei,
    const float* __restrict__ Wm, const float* __restrict__ Wmi,
    const float* __restrict__ bm, const float* __restrict__ bmi, const float* __restrict__ bmh,
    const float* __restrict__ be, const float* __restrict__ bei, const float* __restrict__ beh,
    float* __restrict__ Wse, float* __restrict__ Wre, float* __restrict__ Wcm,
    float* __restrict__ bcm, float* __restrict__ bce){
  int bid = blockIdx.x, tid = threadIdx.x;
  if (bid < 2048){
    int idx = bid*256 + tid;            // 0..524287
    int half = idx >> 18;               // 0: Wse, 1: Wre
    int j = idx & 262143;
    int k = j >> 10, n = j & 1023;
    const float* Wrow = We + (half*256 + k)*128;
    float s = 0.f;
    for (int d = 0; d < 128; ++d) s += Wrow[d] * Wei[d*1024 + n];
    (half ? Wre : Wse)[k*1024 + n] = s;
  } else if (bid < 2064){
    int idx = (bid-2048)*256 + tid;     // 0..4095
    int d = idx >> 10, n = idx & 1023;
    float s = 0.f;
    for (int j = 0; j < 128; ++j) s += Wm[d*128 + j] * Wmi[j*1024 + n];
    Wcm[idx] = s;
  } else if (bid < 2068){
    int n = (bid-2064)*256 + tid;
    float s = bmi[n] + bmh[n];
    for (int j = 0; j < 128; ++j) s += bm[j] * Wmi[j*1024 + n];
    bcm[n] = s;
  } else {
    int n = (bid-2068)*256 + tid;
    float s = bei[n] + beh[n];
    for (int j = 0; j < 128; ++j) s += be[j] * Wei[j*1024 + n];
    bce[n] = s;
  }
}

// ---------------------------------------------------------------------------
// prep_b: pack K=256 x N matrices (fp32, ld=1024) into bf16 MFMA B-frag layout
// dst[((nt*8+kt)*64+lane)*8 + j] = S[kt*32 + (lane>>4)*8 + j][nt*16 + (lane&15)]
// grid 512 x 256
__device__ __forceinline__ void pack_one(const float* __restrict__ S,
                                         unsigned short* __restrict__ dst, int id, int n){
  int lane = id & 63, kt = (id >> 6) & 7;
  int k0 = kt*32 + ((lane >> 4) << 3);
  unsigned int wb[4];
  #pragma unroll
  for (int p = 0; p < 4; ++p){
    unsigned short a = f2bf(S[(k0+2*p  )*1024 + n]);
    unsigned short b = f2bf(S[(k0+2*p+1)*1024 + n]);
    wb[p] = (unsigned int)a | ((unsigned int)b << 16);
  }
  ((uint4*)dst)[id] = make_uint4(wb[0], wb[1], wb[2], wb[3]);
}

__global__ __launch_bounds__(256) void prep_b(
    const float* __restrict__ Wmh, const float* __restrict__ Weh,
    const float* __restrict__ Wse, const float* __restrict__ Wre,
    unsigned short* __restrict__ pWmh, unsigned short* __restrict__ pWeh,
    unsigned short* __restrict__ pWsr){
  int gid = blockIdx.x*256 + threadIdx.x;   // 0..131071
  if (gid < 32768){
    int id = gid;
    int n = (id >> 9)*16 + (id & 15);
    pack_one(Wmh, pWmh, id, n);
  } else if (gid < 65536){
    int id = gid - 32768;
    int n = (id >> 9)*16 + (id & 15);
    pack_one(Weh, pWeh, id, n);
  } else {
    int id = gid - 65536;                   // nt 0..127
    int ng = (id >> 9)*16 + (id & 15);      // 0..2047
    const float* S = (ng < 1024) ? Wse : Wre;
    pack_one(S, pWsr, id, ng & 1023);
  }
}

// ---------------------------------------------------------------------------
// motion_lstm: 20 blocks x 256 thr (4 waves). Block = 16 sequences (seq=b*20+n).
// Wave w owns h-cols [64w,64w+64): 4 h-tiles x 4 gates = 16 MFMA tiles.
// Writes hm bf16 [seq*63+t][256].
__global__ __launch_bounds__(256) void motion_lstm(
    const float* __restrict__ X, const float* __restrict__ Wcm,
    const float* __restrict__ bcm, const unsigned short* __restrict__ pWmh,
    unsigned short* __restrict__ hm){
  __shared__ __align__(16) unsigned short hbuf[16*264];   // 8448 B, stride 264 (16B-aligned rows)
  __shared__ float dxs[16*252];                            // [16][63][4]
  __shared__ float sWcm[4*1024];
  __shared__ float sbcm[1024];
  int tid = threadIdx.x, lane = tid & 63, w = tid >> 6;
  int l15 = lane & 15, quad = lane >> 4;
  int s0 = blockIdx.x * 16;

  for (int i = tid; i < 4096; i += 256) sWcm[i] = Wcm[i];
  for (int i = tid; i < 1024; i += 256) sbcm[i] = bcm[i];
  for (int i = tid; i < 16*264; i += 256) hbuf[i] = 0;
  for (int i = tid; i < 16*252; i += 256){
    int m = i / 252; int td = i % 252; int t = td >> 2; int d = td & 3;
    const float* Xp = X + ((s0 + m)*64 + t)*4 + d;   // (b*20+n) == s0+m
    dxs[i] = Xp[4] - Xp[0];
  }
  __syncthreads();

  f32x4 acc[4][4];       // [htl][gate]
  float c[4][4];         // [htl][r]
  #pragma unroll
  for (int a = 0; a < 4; ++a)
    #pragma unroll
    for (int r = 0; r < 4; ++r) c[a][r] = 0.f;

  for (int t = 0; t < TSTEPS; ++t){
    // acc init: xg = dX @ Wcm + bcm
    float dx[4][4];
    #pragma unroll
    for (int r = 0; r < 4; ++r){
      int m = quad*4 + r;
      #pragma unroll
      for (int d = 0; d < 4; ++d) dx[r][d] = dxs[m*252 + t*4 + d];
    }
    #pragma unroll
    for (int htl = 0; htl < 4; ++htl){
      int cb = w*64 + htl*16 + l15;
      #pragma unroll
      for (int g = 0; g < 4; ++g){
        int gcol = g*256 + cb;
        float w0 = sWcm[gcol], w1 = sWcm[1024+gcol], w2 = sWcm[2048+gcol], w3 = sWcm[3072+gcol];
        float bb = sbcm[gcol];
        f32x4 a;
        #pragma unroll
        for (int r = 0; r < 4; ++r)
          a[r] = bb + dx[r][0]*w0 + dx[r][1]*w1 + dx[r][2]*w2 + dx[r][3]*w3;
        acc[htl][g] = a;
      }
    }
    // K loop: gates += h @ Wmh
    #pragma unroll
    for (int kt = 0; kt < 8; ++kt){
      bf16x8 af = as_frag(*(const uint4*)&hbuf[l15*264 + kt*32 + quad*8]);
      #pragma unroll
      for (int htl = 0; htl < 4; ++htl){
        #pragma unroll
        for (int g = 0; g < 4; ++g){
          int nt = g*16 + w*4 + htl;
          bf16x8 bfr = as_frag(*(const uint4*)&pWmh[((nt*8 + kt)*64 + lane)*8]);
          acc[htl][g] = __builtin_amdgcn_mfma_f32_16x16x32_bf16(af, bfr, acc[htl][g], 0, 0, 0);
        }
      }
    }
    __syncthreads();
    // elementwise update + h out
    #pragma unroll
    for (int htl = 0; htl < 4; ++htl){
      int col = w*64 + htl*16 + l15;
      #pragma unroll
      for (int r = 0; r < 4; ++r){
        int row = quad*4 + r;
        float iv = sigmf(acc[htl][0][r]);
        float fv = sigmf(acc[htl][1][r]);
        float gv = tanh_f(acc[htl][2][r]);
        float ov = sigmf(acc[htl][3][r]);
        float cc = fv*c[htl][r] + iv*gv;
        c[htl][r] = cc;
        unsigned short hb = f2bf(ov * tanh_f(cc));
        hbuf[row*264 + col] = hb;
        hm[((s0 + row)*63 + t)*256 + col] = hb;
      }
    }
    __syncthreads();
  }
}

// ---------------------------------------------------------------------------
// gsr_gemm: gsr = hm @ [Wse|Wre]  (M=20160, N=2048, K=256), bf16 out.
// Output layout gate-interleaved per half: col' = half*1024 + hcol*4 + gate.
// Block 256 thr = 4 waves (2x2), block tile 64M x 128N. grid 315*16.
__global__ __launch_bounds__(256) void gsr_gemm(
    const unsigned short* __restrict__ hm, const unsigned short* __restrict__ pWsr,
    unsigned short* __restrict__ gsr){
  int tid = threadIdx.x, lane = tid & 63, wid = tid >> 6;
  int l15 = lane & 15, quad = lane >> 4;
  int bm = blockIdx.x % 315, bn = blockIdx.x / 315;
  int rowbase = bm*64 + (wid >> 1)*32;
  int ntbase  = bn*8  + (wid & 1)*4;
  f32x4 acc[2][4] = {};
  #pragma unroll
  for (int kt = 0; kt < 8; ++kt){
    bf16x8 af[2];
    #pragma unroll
    for (int mt = 0; mt < 2; ++mt){
      int row = rowbase + mt*16 + l15;
      af[mt] = as_frag(*(const uint4*)&hm[row*256 + kt*32 + quad*8]);
    }
    #pragma unroll
    for (int nt = 0; nt < 4; ++nt){
      bf16x8 bfr = as_frag(*(const uint4*)&pWsr[(((ntbase+nt)*8 + kt)*64 + lane)*8]);
      #pragma unroll
      for (int mt = 0; mt < 2; ++mt)
        acc[mt][nt] = __builtin_amdgcn_mfma_f32_16x16x32_bf16(af[mt], bfr, acc[mt][nt], 0, 0, 0);
    }
  }
  #pragma unroll
  for (int mt = 0; mt < 2; ++mt)
    #pragma unroll
    for (int nt = 0; nt < 4; ++nt){
      int col = (ntbase+nt)*16 + l15;
      int half = col >> 10, ch = col & 1023;
      int colp = (half << 10) | ((ch & 255)*4 + (ch >> 8));
      #pragma unroll
      for (int r = 0; r < 4; ++r){
        int row = rowbase + mt*16 + quad*4 + r;
        gsr[row*2048 + colp] = f2bf(acc[mt][nt][r]);
      }
    }
}

// ---------------------------------------------------------------------------
// edge_lstm: 192 blocks (16 b x 12) x 1024 thr (16 waves). M=32 edges/block.
// Wave w owns h-cols [16w,16w+16): tiles nt = g*16+w, mt=0..1. 2 barriers/step.
// Gate inputs gathered per step from gsr via LDS stage (gr: 20 nodes, gs: 3 senders).
__global__ __launch_bounds__(1024) void edge_lstm(
    const unsigned short* __restrict__ gsr, const float* __restrict__ bce,
    const unsigned short* __restrict__ pWeh, const float* __restrict__ Wf,
    const float* __restrict__ bfp, float* __restrict__ Aout){
  __shared__ __align__(16) unsigned short hbuf[32*264];   // 16896 B
  __shared__ __align__(16) unsigned short grs[20*1032];   // 41280 B (gr half, gate-interleaved)
  __shared__ __align__(16) unsigned short gss[3*1032];    // 6192 B  (gs rows smin..smin+2)
  int tid = threadIdx.x, lane = tid & 63, w = tid >> 6;
  int l15 = lane & 15, quad = lane >> 4;
  int b = blockIdx.x / 12, jb = blockIdx.x % 12;
  int e0 = jb * 32;
  int smin = e0 / 19;

  int sRel[2][4], rIdx[2][4];
  #pragma unroll
  for (int mt = 0; mt < 2; ++mt)
    #pragma unroll
    for (int r = 0; r < 4; ++r){
      int m = mt*16 + quad*4 + r;
      int e = e0 + m; if (e > 379) e = 379;
      int s = e / 19; int rr = e % 19; int rec = rr + (rr >= s ? 1 : 0);
      sRel[mt][r] = s - smin;
      rIdx[mt][r] = rec;
    }
  float breg[4];
  #pragma unroll
  for (int g = 0; g < 4; ++g) breg[g] = bce[g*256 + w*16 + l15];
  for (int i = tid; i < 32*264; i += 1024) hbuf[i] = 0;

  float c[2][4];
  #pragma unroll
  for (int mt = 0; mt < 2; ++mt)
    #pragma unroll
    for (int r = 0; r < 4; ++r) c[mt][r] = 0.f;
  f32x4 acc[2][4];
  int hc4 = (w*16 + l15)*4;
  __syncthreads();

  for (int t = 0; t < TSTEPS; ++t){
    // stage gather rows for this t
    for (int i = tid; i < 2944; i += 1024){
      unsigned short* dstp; int srcoff;
      if (i < 2560){
        int node = i >> 7, c8 = i & 127;
        srcoff = ((b*20 + node)*63 + t)*2048 + 1024 + c8*8;
        dstp = &grs[node*1032 + c8*8];
      } else {
        int ii = i - 2560; int sm = ii >> 7, c8 = ii & 127;
        int node = smin + sm; if (node > 19) node = 19;
        srcoff = ((b*20 + node)*63 + t)*2048 + c8*8;
        dstp = &gss[sm*1032 + c8*8];
      }
      *(uint4*)dstp = *(const uint4*)&gsr[srcoff];
    }
    __syncthreads();
    // acc init: xg(sender)+xg(receiver)+bias  (4 gates per 8B read)
    #pragma unroll
    for (int mt = 0; mt < 2; ++mt){
      #pragma unroll
      for (int r = 0; r < 4; ++r){
        uint2 gv = *(const uint2*)&gss[sRel[mt][r]*1032 + hc4];
        uint2 rv = *(const uint2*)&grs[rIdx[mt][r]*1032 + hc4];
        acc[mt][0][r] = bf2f((unsigned short)(gv.x & 0xffff)) + bf2f((unsigned short)(rv.x & 0xffff)) + breg[0];
        acc[mt][1][r] = bf2f((unsigned short)(gv.x >> 16))    + bf2f((unsigned short)(rv.x >> 16))    + breg[1];
        acc[mt][2][r] = bf2f((unsigned short)(gv.y & 0xffff)) + bf2f((unsigned short)(rv.y & 0xffff)) + breg[2];
        acc[mt][3][r] = bf2f((unsigned short)(gv.y >> 16))    + bf2f((unsigned short)(rv.y >> 16))    + breg[3];
      }
    }
    // K loop: gates += h @ Weh
    #pragma unroll
    for (int kt = 0; kt < 8; ++kt){
      bf16x8 af[2];
      #pragma unroll
      for (int mt = 0; mt < 2; ++mt)
        af[mt] = as_frag(*(const uint4*)&hbuf[(mt*16 + l15)*264 + kt*32 + quad*8]);
      #pragma unroll
      for (int g = 0; g < 4; ++g){
        int nt = g*16 + w;
        bf16x8 bfr = as_frag(*(const uint4*)&pWeh[((nt*8 + kt)*64 + lane)*8]);
        #pragma unroll
        for (int mt = 0; mt < 2; ++mt)
          acc[mt][g] = __builtin_amdgcn_mfma_f32_16x16x32_bf16(af[mt], bfr, acc[mt][g], 0, 0, 0);
      }
    }
    __syncthreads();
    // LSTM update
    #pragma unroll
    for (int mt = 0; mt < 2; ++mt){
      #pragma unroll
      for (int r = 0; r < 4; ++r){
        int row = mt*16 + quad*4 + r;
        float iv = sigmf(acc[mt][0][r]);
        float fv = sigmf(acc[mt][1][r]);
        float gv = tanh_f(acc[mt][2][r]);
        float ov = sigmf(acc[mt][3][r]);
        float cc = fv*c[mt][r] + iv*gv;
        c[mt][r] = cc;
        hbuf[row*264 + w*16 + l15] = f2bf(ov * tanh_f(cc));
      }
    }
    __syncthreads();
  }
  // epilogue: A[b,e] = sigmoid(h_last . Wf + bf)
  if (tid < 32){
    int e = e0 + tid;
    if (e < 380){
      float s = bfp[0];
      for (int k = 0; k < 256; ++k) s += bf2f(hbuf[tid*264 + k]) * Wf[k];
      Aout[b*380 + e] = sigmf(s);
    }
  }
}

// ---------------------------------------------------------------------------
// finalize: out[b,i,j] = (i==j) ? 0 : 0.5*(A[b,e(i,j)] + A[b,e(j,i)])
__global__ __launch_bounds__(256) void finalize(const float* __restrict__ Aout,
                                                float* __restrict__ out){
  int idx = blockIdx.x*256 + threadIdx.x;
  if (idx >= 16*400) return;
  int b = idx / 400; int ij = idx % 400; int i = ij / 20; int j = ij % 20;
  float v = 0.f;
  if (i != j){
    int e1 = i*19 + j - (j > i ? 1 : 0);
    int e2 = j*19 + i - (i > j ? 1 : 0);
    v = 0.5f*(Aout[b*380 + e1] + Aout[b*380 + e2]);
  }
  out[idx] = v;
}

// ---------------------------------------------------------------------------
extern "C" void kernel_launch(void* const* d_in, const int* in_sizes, int n_in,
                              void* d_out, int out_size, void* d_ws, size_t ws_size,
                              hipStream_t stream){
  (void)in_sizes; (void)n_in; (void)out_size; (void)ws_size;
  const float* X   = (const float*)d_in[0];
  const float* Wm  = (const float*)d_in[3];
  const float* bm  = (const float*)d_in[4];
  const float* Wmi = (const float*)d_in[5];
  const float* bmi = (const float*)d_in[6];
  const float* Wmh = (const float*)d_in[7];
  const float* bmh = (const float*)d_in[8];
  const float* We  = (const float*)d_in[9];
  const float* be  = (const float*)d_in[10];
  const float* Wei = (const float*)d_in[11];
  const float* bei = (const float*)d_in[12];
  const float* Weh = (const float*)d_in[13];
  const float* beh = (const float*)d_in[14];
  const float* Wf  = (const float*)d_in[15];
  const float* bfp = (const float*)d_in[16];

  char* ws = (char*)d_ws;                                // ~97 MB used
  float* Wse = (float*)(ws + 0);                         // 1 MB
  float* Wre = (float*)(ws + 1048576);                   // 1 MB
  float* Wcm = (float*)(ws + 2097152);                   // 16 KB
  float* bcm = (float*)(ws + 2113536);                   // 4 KB
  float* bce = (float*)(ws + 2117632);                   // 4 KB
  unsigned short* pWmh = (unsigned short*)(ws + 2121728);   // 512 KB
  unsigned short* pWeh = (unsigned short*)(ws + 2646016);   // 512 KB
  unsigned short* pWsr = (unsigned short*)(ws + 3170304);   // 1 MB
  unsigned short* hm   = (unsigned short*)(ws + 4218880);   // 10.3 MB
  unsigned short* gsr  = (unsigned short*)(ws + 14540800);  // 82.6 MB
  float* Aout = (float*)(ws + 97116160);                    // 24 KB
  float* out = (float*)d_out;

  hipLaunchKernelGGL(prep_a, dim3(2072), dim3(256), 0, stream,
                     We, Wei, Wm, Wmi, bm, bmi, bmh, be, bei, beh,
                     Wse, Wre, Wcm, bcm, bce);
  hipLaunchKernelGGL(prep_b, dim3(512), dim3(256), 0, stream,
                     Wmh, Weh, Wse, Wre, pWmh, pWeh, pWsr);
  hipLaunchKernelGGL(motion_lstm, dim3(20), dim3(256), 0, stream,
                     X, Wcm, bcm, pWmh, hm);
  hipLaunchKernelGGL(gsr_gemm, dim3(315*16), dim3(256), 0, stream,
                     hm, pWsr, gsr);
  hipLaunchKernelGGL(edge_lstm, dim3(192), dim3(1024), 0, stream,
                     gsr, bce, pWeh, Wf, bfp, Aout);
  hipLaunchKernelGGL(finalize, dim3(25), dim3(256), 0, stream,
                     Aout, out);
}

// Round 2
// 1870.157 us; speedup vs baseline: 1.2025x; 1.2025x over previous
//
#include <hip/hip_runtime.h>
#include <stdint.h>

// Problem constants
#define NBATCH 16
#define NNODE  20
#define TSTEPS 63      // T-1
#define NEDGE  380
#define HID    256
#define G4     1024    // 4*HID

typedef __bf16 bf16x8 __attribute__((ext_vector_type(8)));
typedef float  f32x4  __attribute__((ext_vector_type(4)));

__device__ __forceinline__ float bf2f(unsigned short u){
  union { unsigned int i; float f; } v; v.i = ((unsigned int)u) << 16; return v.f;
}
__device__ __forceinline__ unsigned short f2bf(float f){
  union { float f; unsigned int i; } v; v.f = f;
  return (unsigned short)((v.i + 0x7FFFu + ((v.i >> 16) & 1u)) >> 16);
}
__device__ __forceinline__ bf16x8 as_frag(uint4 v){
  union { uint4 u; bf16x8 b; } c; c.u = v; return c.b;
}
__device__ __forceinline__ float sigmf(float x){ return 1.0f/(1.0f+__expf(-x)); }
__device__ __forceinline__ float tanh_f(float x){ float e=__expf(2.0f*x); return (e-1.0f)/(e+1.0f); }

// ---------------------------------------------------------------------------
// prep_a: combined weights (fp32): Wse=We[0:256]@Wei, Wre=We[256:512]@Wei (plain col),
//   Wcm_gi [4][1024] gate-interleaved (col' = hcol*4+g), bcm_gi, bce_gi interleaved.
//   Also zeroes barrier counters + Afin.
// grid 2097 x 256
__global__ __launch_bounds__(256) void prep_a(
    const float* __restrict__ We, const float* __restrict__ Wei,
    const float* __restrict__ Wm, const float* __restrict__ Wmi,
    const float* __restrict__ bm, const float* __restrict__ bmi, const float* __restrict__ bmh,
    const float* __restrict__ be, const float* __restrict__ bei, const float* __restrict__ beh,
    float* __restrict__ Wse, float* __restrict__ Wre, float* __restrict__ WcmGI,
    float* __restrict__ bcmGI, float* __restrict__ bceGI,
    float* __restrict__ Afin, unsigned int* __restrict__ ectr, unsigned int* __restrict__ mctr){
  int bid = blockIdx.x, tid = threadIdx.x;
  if (bid < 2048){
    int idx = bid*256 + tid;            // 0..524287
    int half = idx >> 18;               // 0: Wse, 1: Wre
    int j = idx & 262143;
    int k = j >> 10, nn = j & 1023;
    const float* Wrow = We + (half*256 + k)*128;
    float s = 0.f;
    for (int d = 0; d < 128; ++d) s += Wrow[d] * Wei[d*1024 + nn];
    (half ? Wre : Wse)[k*1024 + nn] = s;
  } else if (bid < 2064){
    int idx = (bid-2048)*256 + tid;     // 0..4095  -> WcmGI[d][hcol*4+g]
    int d = idx >> 10, ci = idx & 1023;
    int col = (ci & 3)*256 + (ci >> 2);
    float s = 0.f;
    for (int j = 0; j < 128; ++j) s += Wm[d*128 + j] * Wmi[j*1024 + col];
    WcmGI[idx] = s;
  } else if (bid < 2068){
    int ci = (bid-2064)*256 + tid;
    int col = (ci & 3)*256 + (ci >> 2);
    float s = bmi[col] + bmh[col];
    for (int j = 0; j < 128; ++j) s += bm[j] * Wmi[j*1024 + col];
    bcmGI[ci] = s;
  } else if (bid < 2072){
    int ci = (bid-2068)*256 + tid;
    int col = (ci & 3)*256 + (ci >> 2);
    float s = bei[col] + beh[col];
    for (int j = 0; j < 128; ++j) s += be[j] * Wei[j*1024 + col];
    bceGI[ci] = s;
  } else if (bid == 2072){
    if (tid < 64) ectr[tid] = 0u;
    else if (tid < 96) mctr[tid-64] = 0u;
  } else {
    int idx = (bid-2073)*256 + tid;
    if (idx < NBATCH*NEDGE) Afin[idx] = 0.f;
  }
}

// ---------------------------------------------------------------------------
// prep_b packing.
// pack_gi: B-frag pack with gate-interleaved N-block layout:
//   dst uint4 id = (((nb*8+w)*2+tt)*8+kt)*64+lane ; col = (cl&3)*256 + nb*64 + (w*2+tt)*4 + (cl>>2)
__device__ __forceinline__ void pack_gi(const float* __restrict__ W,
                                        unsigned short* __restrict__ dst, int id){
  int lane = id & 63, kt = (id >> 6) & 7, tt = (id >> 9) & 1, w = (id >> 10) & 7, nb = id >> 13;
  int cl = lane & 15, q = lane >> 4;
  int gcol = (cl & 3)*256 + nb*64 + (w*2 + tt)*4 + (cl >> 2);
  int k0 = kt*32 + q*8;
  unsigned int wb[4];
  #pragma unroll
  for (int p = 0; p < 4; ++p){
    unsigned short a = f2bf(W[(k0+2*p  )*1024 + gcol]);
    unsigned short b = f2bf(W[(k0+2*p+1)*1024 + gcol]);
    wb[p] = (unsigned int)a | ((unsigned int)b << 16);
  }
  ((uint4*)dst)[id] = make_uint4(wb[0], wb[1], wb[2], wb[3]);
}

// pack_one: plain-col pack for gsr_gemm's B (unchanged from round 1)
__device__ __forceinline__ void pack_one(const float* __restrict__ S,
                                         unsigned short* __restrict__ dst, int id, int n){
  int lane = id & 63, kt = (id >> 6) & 7;
  int k0 = kt*32 + ((lane >> 4) << 3);
  unsigned int wb[4];
  #pragma unroll
  for (int p = 0; p < 4; ++p){
    unsigned short a = f2bf(S[(k0+2*p  )*1024 + n]);
    unsigned short b = f2bf(S[(k0+2*p+1)*1024 + n]);
    wb[p] = (unsigned int)a | ((unsigned int)b << 16);
  }
  ((uint4*)dst)[id] = make_uint4(wb[0], wb[1], wb[2], wb[3]);
}

__global__ __launch_bounds__(256) void prep_b(
    const float* __restrict__ Wmh, const float* __restrict__ Weh,
    const float* __restrict__ Wse, const float* __restrict__ Wre,
    unsigned short* __restrict__ pWmh, unsigned short* __restrict__ pWeh,
    unsigned short* __restrict__ pWsr){
  int gid = blockIdx.x*256 + threadIdx.x;   // 0..131071
  if (gid < 32768){
    pack_gi(Wmh, pWmh, gid);
  } else if (gid < 65536){
    pack_gi(Weh, pWeh, gid - 32768);
  } else {
    int id = gid - 65536;                   // nt 0..127 plain cols
    int ng = (id >> 9)*16 + (id & 15);      // 0..2047
    const float* S = (ng < 1024) ? Wse : Wre;
    pack_one(S, pWsr, id, ng & 1023);
  }
}

// ---------------------------------------------------------------------------
// motion_lstm (persistent, register-resident weights, 4-block n-groups):
// grid 128 = 32 m-tiles (10 seqs) x 4 n-slices (64 hcols). 512 thr = 8 waves.
// Wave w owns nt tiles {2w, 2w+1}; tile cols gate-interleaved (cl = hsub*4+g).
// h exchange via hm itself (distinct address per t); barrier = mctr[m] >= 4t.
__global__ __launch_bounds__(512, 2) void motion_lstm(
    const float* __restrict__ X, const float* __restrict__ WcmGI,
    const float* __restrict__ bcmGI, const unsigned short* __restrict__ pWmh,
    unsigned short* __restrict__ hm, unsigned int* __restrict__ mctr){
  __shared__ __align__(16) unsigned short hst[16*264];
  __shared__ float dxs[10*252];
  __shared__ __align__(16) float sWc[4*256];
  __shared__ __align__(16) float sbc[256];
  __shared__ __align__(16) float scr[8*2*320];
  int tid = threadIdx.x, lane = tid & 63, w = tid >> 6;
  int l15 = lane & 15, quad = lane >> 4;
  int row16 = lane >> 2, h4 = lane & 3;
  int m = blockIdx.x & 31, n = blockIdx.x >> 5;
  int s0 = m*10;
  unsigned int* ctr = mctr + m;

  uint4 wreg[2][8];
  #pragma unroll
  for (int tt = 0; tt < 2; ++tt)
    #pragma unroll
    for (int kt = 0; kt < 8; ++kt)
      wreg[tt][kt] = ((const uint4*)pWmh)[(((n*8 + w)*2 + tt)*8 + kt)*64 + lane];

  uint4 z4 = make_uint4(0,0,0,0);
  for (int i = tid; i < 528; i += 512) ((uint4*)hst)[i] = z4;
  for (int i = tid; i < 1024; i += 512) sWc[i] = WcmGI[(i >> 8)*1024 + n*256 + (i & 255)];
  if (tid < 256) sbc[tid] = bcmGI[n*256 + tid];
  for (int i = tid; i < 2520; i += 512){
    int sl = i / 252; int r = i % 252; int t = r >> 2; int d = r & 3;
    const float* Xp = X + (((size_t)(s0 + sl)*64 + t)*4 + d);
    dxs[i] = Xp[4] - Xp[0];
  }
  __syncthreads();

  float ce[2] = {0.f, 0.f};
  int sl = row16 < 10 ? row16 : 9;

  for (int t = 0; t < TSTEPS; ++t){
    if (t > 0){
      if (tid == 0){
        unsigned int tgt = 4u*(unsigned)t;
        while (__hip_atomic_load(ctr, __ATOMIC_ACQUIRE, __HIP_MEMORY_SCOPE_AGENT) < tgt)
          __builtin_amdgcn_s_sleep(8);
      }
      __syncthreads();
      for (int i = tid; i < 320; i += 512){
        int r = i >> 5, c = i & 31;
        uint4 v = *(const uint4*)&hm[(((size_t)(s0 + r)*63) + (t-1))*256 + c*8];
        *(uint4*)&hst[r*264 + c*8] = v;
      }
    }
    __syncthreads();

    f32x4 acc0 = {0.f,0.f,0.f,0.f}, acc1 = {0.f,0.f,0.f,0.f};
    #pragma unroll
    for (int kt = 0; kt < 8; ++kt){
      bf16x8 a = as_frag(*(const uint4*)&hst[l15*264 + kt*32 + quad*8]);
      acc0 = __builtin_amdgcn_mfma_f32_16x16x32_bf16(a, as_frag(wreg[0][kt]), acc0, 0, 0, 0);
      acc1 = __builtin_amdgcn_mfma_f32_16x16x32_bf16(a, as_frag(wreg[1][kt]), acc1, 0, 0, 0);
    }
    int wb = w*640;
    #pragma unroll
    for (int r = 0; r < 4; ++r){
      scr[wb +       (quad*4 + r)*20 + l15] = acc0[r];
      scr[wb + 320 + (quad*4 + r)*20 + l15] = acc1[r];
    }
    #pragma unroll
    for (int tt = 0; tt < 2; ++tt){
      int tile = w*2 + tt;
      f32x4 v = *(const f32x4*)&scr[wb + tt*320 + row16*20 + h4*4];
      f32x4 bias = *(const f32x4*)&sbc[tile*16 + h4*4];
      float g0 = v[0] + bias[0], g1 = v[1] + bias[1], g2 = v[2] + bias[2], g3 = v[3] + bias[3];
      #pragma unroll
      for (int d = 0; d < 4; ++d){
        float dx = dxs[sl*252 + t*4 + d];
        f32x4 wv = *(const f32x4*)&sWc[d*256 + tile*16 + h4*4];
        g0 += dx*wv[0]; g1 += dx*wv[1]; g2 += dx*wv[2]; g3 += dx*wv[3];
      }
      float iv = sigmf(g0), fv = sigmf(g1), gv = tanh_f(g2), ov = sigmf(g3);
      float cc = fv*ce[tt] + iv*gv; ce[tt] = cc;
      float h = ov*tanh_f(cc);
      if (row16 < 10)
        hm[(((size_t)(s0 + row16)*63) + t)*256 + n*64 + tile*4 + h4] = f2bf(h);
    }
    __syncthreads();
    if (t < 62 && tid == 0)
      __hip_atomic_fetch_add(ctr, 1u, __ATOMIC_RELEASE, __HIP_MEMORY_SCOPE_AGENT);
  }
}

// ---------------------------------------------------------------------------
// gsr_gemm: gsr = hm @ [Wse|Wre]  (M=20160, N=2048, K=256), bf16 out,
// gate-interleaved per half: col' = half*1024 + hcol*4 + gate. (round-1, verified)
__global__ __launch_bounds__(256) void gsr_gemm(
    const unsigned short* __restrict__ hm, const unsigned short* __restrict__ pWsr,
    unsigned short* __restrict__ gsr){
  int tid = threadIdx.x, lane = tid & 63, wid = tid >> 6;
  int l15 = lane & 15, quad = lane >> 4;
  int bm = blockIdx.x % 315, bn = blockIdx.x / 315;
  int rowbase = bm*64 + (wid >> 1)*32;
  int ntbase  = bn*8  + (wid & 1)*4;
  f32x4 acc[2][4] = {};
  #pragma unroll
  for (int kt = 0; kt < 8; ++kt){
    bf16x8 af[2];
    #pragma unroll
    for (int mt = 0; mt < 2; ++mt){
      int row = rowbase + mt*16 + l15;
      af[mt] = as_frag(*(const uint4*)&hm[(size_t)row*256 + kt*32 + quad*8]);
    }
    #pragma unroll
    for (int nt = 0; nt < 4; ++nt){
      bf16x8 bfr = as_frag(*(const uint4*)&pWsr[(((size_t)(ntbase+nt)*8 + kt)*64 + lane)*8]);
      #pragma unroll
      for (int mt = 0; mt < 2; ++mt)
        acc[mt][nt] = __builtin_amdgcn_mfma_f32_16x16x32_bf16(af[mt], bfr, acc[mt][nt], 0, 0, 0);
    }
  }
  #pragma unroll
  for (int mt = 0; mt < 2; ++mt)
    #pragma unroll
    for (int nt = 0; nt < 4; ++nt){
      int col = (ntbase+nt)*16 + l15;
      int half = col >> 10, ch = col & 1023;
      int colp = (half << 10) | ((ch & 255)*4 + (ch >> 8));
      #pragma unroll
      for (int r = 0; r < 4; ++r){
        int row = rowbase + mt*16 + quad*4 + r;
        gsr[(size_t)row*2048 + colp] = f2bf(acc[mt][nt][r]);
      }
    }
}

// ---------------------------------------------------------------------------
// edge_lstm (persistent): grid 256 = 16 b x 4 m-tiles (95 edges) x 4 n-slices.
// 512 thr = 8 waves; wave w owns nt {2w,2w+1} (each = 4 hcols x 4 gates).
// Weights register-resident (64 VGPR/lane). h exchange via hb[2] parity buffers;
// group barrier ectr[b*4+m] >= 4t; partners at bid ≡ same (mod 8) -> same XCD.
__global__ __launch_bounds__(512, 2) void edge_lstm(
    const unsigned short* __restrict__ gsr, const float* __restrict__ bceGI,
    const unsigned short* __restrict__ pWeh, const float* __restrict__ Wf,
    unsigned short* __restrict__ hb, float* __restrict__ Afin,
    unsigned int* __restrict__ ectr){
  __shared__ __align__(16) unsigned short hst[96*264];        // 50688 B
  __shared__ __align__(16) unsigned short gbuf[2*25*264];     // 26400 B (dbuf gather)
  __shared__ __align__(16) float scr[8*2*320];                // 20480 B
  __shared__ __align__(16) float sbce[256];
  __shared__ __align__(16) float sWf[64];
  int tid = threadIdx.x, lane = tid & 63, w = tid >> 6;
  int l15 = lane & 15, quad = lane >> 4;
  int row16 = lane >> 2, h4 = lane & 3;
  int bid = blockIdx.x;
  int n = bid >> 6, G = bid & 63, b = G >> 2, m = G & 3;
  int e0 = m*95;
  unsigned int* ctr = ectr + G;

  uint4 wreg[2][8];
  #pragma unroll
  for (int tt = 0; tt < 2; ++tt)
    #pragma unroll
    for (int kt = 0; kt < 8; ++kt)
      wreg[tt][kt] = ((const uint4*)pWeh)[(((n*8 + w)*2 + tt)*8 + kt)*64 + lane];

  if (tid < 256) sbce[tid] = bceGI[n*256 + tid];
  if (tid < 64)  sWf[tid]  = Wf[n*64 + tid];
  uint4 z4 = make_uint4(0,0,0,0);
  for (int i = tid; i < 3168; i += 512) ((uint4*)hst)[i] = z4;

  int srel[6], rrec[6];
  #pragma unroll
  for (int mt = 0; mt < 6; ++mt){
    int row = mt*16 + row16;
    int e = e0 + (row < 95 ? row : 94);
    int s = e / 19; int rr = e - s*19;
    srel[mt] = s - m*5;
    rrec[mt] = rr + (rr >= s ? 1 : 0);
  }

  // gather stage t=0 into gbuf[0]
  {
    uint4 gp[2];
    #pragma unroll
    for (int j = 0; j < 2; ++j){
      int i = tid + j*512;
      if (i < 800){
        int r = i >> 5, c = i & 31;
        int node = r < 5 ? m*5 + r : r - 5;
        int half = r < 5 ? 0 : 1024;
        gp[j] = *(const uint4*)&gsr[(((size_t)(b*20 + node)*63) + 0)*2048 + half + n*256 + c*8];
      }
    }
    #pragma unroll
    for (int j = 0; j < 2; ++j){
      int i = tid + j*512;
      if (i < 800){
        int r = i >> 5, c = i & 31;
        *(uint4*)&gbuf[r*264 + c*8] = gp[j];
      }
    }
  }
  __syncthreads();

  float ce[2][6];
  float epi[6];
  #pragma unroll
  for (int tt = 0; tt < 2; ++tt)
    #pragma unroll
    for (int mt = 0; mt < 6; ++mt) ce[tt][mt] = 0.f;
  #pragma unroll
  for (int mt = 0; mt < 6; ++mt) epi[mt] = 0.f;

  for (int t = 0; t < TSTEPS; ++t){
    if (t > 0){
      if (tid == 0){
        unsigned int tgt = 4u*(unsigned)t;
        while (__hip_atomic_load(ctr, __ATOMIC_ACQUIRE, __HIP_MEMORY_SCOPE_AGENT) < tgt)
          __builtin_amdgcn_s_sleep(8);
      }
      __syncthreads();
      int pp = (t-1) & 1;
      const unsigned short* hbp = hb + (((size_t)pp*16 + b)*4 + m)*96*256;
      for (int i = tid; i < 3072; i += 512){
        int r = i >> 5, c = i & 31;
        uint4 v = *(const uint4*)&hbp[r*256 + c*8];
        *(uint4*)&hst[r*264 + c*8] = v;
      }
    }
    // prefetch gather for t+1 (global -> regs; LDS write after K-loop)
    uint4 gp[2];
    int tq = t + 1;
    bool pf = (tq < TSTEPS);
    if (pf){
      #pragma unroll
      for (int j = 0; j < 2; ++j){
        int i = tid + j*512;
        if (i < 800){
          int r = i >> 5, c = i & 31;
          int node = r < 5 ? m*5 + r : r - 5;
          int half = r < 5 ? 0 : 1024;
          gp[j] = *(const uint4*)&gsr[(((size_t)(b*20 + node)*63) + tq)*2048 + half + n*256 + c*8];
        }
      }
    }
    __syncthreads();

    f32x4 acc[2][6];
    #pragma unroll
    for (int mt = 0; mt < 6; ++mt){ acc[0][mt] = (f32x4){0,0,0,0}; acc[1][mt] = (f32x4){0,0,0,0}; }
    #pragma unroll
    for (int kt = 0; kt < 8; ++kt){
      bf16x8 a[6];
      #pragma unroll
      for (int mt = 0; mt < 6; ++mt)
        a[mt] = as_frag(*(const uint4*)&hst[(mt*16 + l15)*264 + kt*32 + quad*8]);
      #pragma unroll
      for (int mt = 0; mt < 6; ++mt){
        acc[0][mt] = __builtin_amdgcn_mfma_f32_16x16x32_bf16(a[mt], as_frag(wreg[0][kt]), acc[0][mt], 0, 0, 0);
        acc[1][mt] = __builtin_amdgcn_mfma_f32_16x16x32_bf16(a[mt], as_frag(wreg[1][kt]), acc[1][mt], 0, 0, 0);
      }
    }
    if (pf){
      unsigned short* gb = &gbuf[(tq & 1)*6600];
      #pragma unroll
      for (int j = 0; j < 2; ++j){
        int i = tid + j*512;
        if (i < 800){
          int r = i >> 5, c = i & 31;
          *(uint4*)&gb[r*264 + c*8] = gp[j];
        }
      }
    }
    // readback + LSTM update
    int bufo = (t & 1)*6600;
    int wb = w*640;
    unsigned short* hbc = hb + (((size_t)(t & 1)*16 + b)*4 + m)*96*256;
    #pragma unroll
    for (int mt = 0; mt < 6; ++mt){
      #pragma unroll
      for (int r = 0; r < 4; ++r){
        scr[wb +       (quad*4 + r)*20 + l15] = acc[0][mt][r];
        scr[wb + 320 + (quad*4 + r)*20 + l15] = acc[1][mt][r];
      }
      #pragma unroll
      for (int tt = 0; tt < 2; ++tt){
        int tile = w*2 + tt;
        int tb = tile*16 + h4*4;
        f32x4 v = *(const f32x4*)&scr[wb + tt*320 + row16*20 + h4*4];
        uint2 gs = *(const uint2*)&gbuf[bufo + srel[mt]*264 + tb];
        uint2 gr = *(const uint2*)&gbuf[bufo + (5 + rrec[mt])*264 + tb];
        f32x4 bias = *(const f32x4*)&sbce[tb];
        float g0 = v[0] + bias[0] + bf2f((unsigned short)(gs.x & 0xffff)) + bf2f((unsigned short)(gr.x & 0xffff));
        float g1 = v[1] + bias[1] + bf2f((unsigned short)(gs.x >> 16))    + bf2f((unsigned short)(gr.x >> 16));
        float g2 = v[2] + bias[2] + bf2f((unsigned short)(gs.y & 0xffff)) + bf2f((unsigned short)(gr.y & 0xffff));
        float g3 = v[3] + bias[3] + bf2f((unsigned short)(gs.y >> 16))    + bf2f((unsigned short)(gr.y >> 16));
        float iv = sigmf(g0), fv = sigmf(g1), gv = tanh_f(g2), ov = sigmf(g3);
        float cc = fv*ce[tt][mt] + iv*gv; ce[tt][mt] = cc;
        float h = ov*tanh_f(cc);
        int row = mt*16 + row16;
        if (t < 62){
          hbc[row*256 + n*64 + tile*4 + h4] = f2bf(h);
        } else {
          epi[mt] += h * sWf[tile*4 + h4];
        }
      }
    }
    __syncthreads();
    if (t < 62 && tid == 0)
      __hip_atomic_fetch_add(ctr, 1u, __ATOMIC_RELEASE, __HIP_MEMORY_SCOPE_AGENT);
  }
  // epilogue: per-edge partial dot with Wf -> atomic accumulate
  #pragma unroll
  for (int mt = 0; mt < 6; ++mt){
    float v = epi[mt];
    v += __shfl_xor(v, 1);
    v += __shfl_xor(v, 2);
    int row = mt*16 + row16;
    if (h4 == 0 && row < 95)
      atomicAdd(&Afin[b*380 + e0 + row], v);
  }
}

// ---------------------------------------------------------------------------
// finalize: out[b,i,j] = (i==j) ? 0 : 0.5*(sig(A[e1]+bf) + sig(A[e2]+bf))
__global__ __launch_bounds__(256) void finalize(const float* __restrict__ Afin,
                                                const float* __restrict__ bfp,
                                                float* __restrict__ out){
  int idx = blockIdx.x*256 + threadIdx.x;
  if (idx >= 16*400) return;
  int b = idx / 400; int ij = idx % 400; int i = ij / 20; int j = ij % 20;
  float v = 0.f;
  if (i != j){
    int e1 = i*19 + j - (j > i ? 1 : 0);
    int e2 = j*19 + i - (i > j ? 1 : 0);
    float bf = bfp[0];
    v = 0.5f*(sigmf(Afin[b*380 + e1] + bf) + sigmf(Afin[b*380 + e2] + bf));
  }
  out[idx] = v;
}

// ---------------------------------------------------------------------------
extern "C" void kernel_launch(void* const* d_in, const int* in_sizes, int n_in,
                              void* d_out, int out_size, void* d_ws, size_t ws_size,
                              hipStream_t stream){
  (void)in_sizes; (void)n_in; (void)out_size; (void)ws_size;
  const float* X   = (const float*)d_in[0];
  const float* Wm  = (const float*)d_in[3];
  const float* bm  = (const float*)d_in[4];
  const float* Wmi = (const float*)d_in[5];
  const float* bmi = (const float*)d_in[6];
  const float* Wmh = (const float*)d_in[7];
  const float* bmh = (const float*)d_in[8];
  const float* We  = (const float*)d_in[9];
  const float* be  = (const float*)d_in[10];
  const float* Wei = (const float*)d_in[11];
  const float* bei = (const float*)d_in[12];
  const float* Weh = (const float*)d_in[13];
  const float* beh = (const float*)d_in[14];
  const float* Wf  = (const float*)d_in[15];
  const float* bfp = (const float*)d_in[16];

  char* ws = (char*)d_ws;
  float* Wse   = (float*)(ws + 0);                          // 1 MB
  float* Wre   = (float*)(ws + 1048576);                    // 1 MB
  float* WcmGI = (float*)(ws + 2097152);                    // 16 KB
  float* bcmGI = (float*)(ws + 2113536);                    // 4 KB
  float* bceGI = (float*)(ws + 2117632);                    // 4 KB
  unsigned short* pWmh = (unsigned short*)(ws + 2121728);   // 512 KB
  unsigned short* pWeh = (unsigned short*)(ws + 2646016);   // 512 KB
  unsigned short* pWsr = (unsigned short*)(ws + 3170304);   // 1 MB
  unsigned short* hm   = (unsigned short*)(ws + 4218880);   // 10.3 MB
  unsigned short* gsr  = (unsigned short*)(ws + 14540800);  // 82.6 MB
  unsigned short* hb   = (unsigned short*)(ws + 97116160);  // 6.3 MB
  float* Afin          = (float*)(ws + 103407616);          // 24 KB
  unsigned int* ectr   = (unsigned int*)(ws + 103432192);   // 256 B
  unsigned int* mctr   = (unsigned int*)(ws + 103432448);   // 128 B
  float* out = (float*)d_out;

  hipLaunchKernelGGL(prep_a, dim3(2097), dim3(256), 0, stream,
                     We, Wei, Wm, Wmi, bm, bmi, bmh, be, bei, beh,
                     Wse, Wre, WcmGI, bcmGI, bceGI, Afin, ectr, mctr);
  hipLaunchKernelGGL(prep_b, dim3(512), dim3(256), 0, stream,
                     Wmh, Weh, Wse, Wre, pWmh, pWeh, pWsr);
  {
    void* margs[] = {(void*)&X, (void*)&WcmGI, (void*)&bcmGI, (void*)&pWmh,
                     (void*)&hm, (void*)&mctr};
    hipLaunchCooperativeKernel(reinterpret_cast<void*>(motion_lstm),
                               dim3(128), dim3(512), margs, 0, stream);
  }
  hipLaunchKernelGGL(gsr_gemm, dim3(315*16), dim3(256), 0, stream,
                     hm, pWsr, gsr);
  {
    void* eargs[] = {(void*)&gsr, (void*)&bceGI, (void*)&pWeh, (void*)&Wf,
                     (void*)&hb, (void*)&Afin, (void*)&ectr};
    hipLaunchCooperativeKernel(reinterpret_cast<void*>(edge_lstm),
                               dim3(256), dim3(512), eargs, 0, stream);
  }
  hipLaunchKernelGGL(finalize, dim3(25), dim3(256), 0, stream,
                     Afin, bfp, out);
}

// Round 3
// 1157.568 us; speedup vs baseline: 1.9428x; 1.6156x over previous
//
#include <hip/hip_runtime.h>
#include <stdint.h>

// Problem constants
#define NBATCH 16
#define NNODE  20
#define TSTEPS 63      // T-1
#define NEDGE  380
#define HID    256
#define G4     1024    // 4*HID
#define RS     280     // hst row stride in shorts (140 words ≡ 12 mod 32: 2-way max on b128 reads)

typedef __bf16 bf16x8 __attribute__((ext_vector_type(8)));
typedef float  f32x4  __attribute__((ext_vector_type(4)));

__device__ __forceinline__ float bf2f(unsigned short u){
  union { unsigned int i; float f; } v; v.i = ((unsigned int)u) << 16; return v.f;
}
__device__ __forceinline__ unsigned short f2bf(float f){
  union { float f; unsigned int i; } v; v.f = f;
  return (unsigned short)((v.i + 0x7FFFu + ((v.i >> 16) & 1u)) >> 16);
}
__device__ __forceinline__ bf16x8 as_frag(uint4 v){
  union { uint4 u; bf16x8 b; } c; c.u = v; return c.b;
}
__device__ __forceinline__ float sigmf(float x){ return 1.0f/(1.0f+__expf(-x)); }
__device__ __forceinline__ float tanh_f(float x){ float e=__expf(2.0f*x); return (e-1.0f)/(e+1.0f); }

// Relaxed agent-scope ops: per-access sc1 (LLC = device coherence point),
// NO cache-wide buffer_inv / buffer_wbl2 (those were the R2 19.5us/step killer).
__device__ __forceinline__ unsigned long long load_ax(const unsigned long long* p){
  return __hip_atomic_load(p, __ATOMIC_RELAXED, __HIP_MEMORY_SCOPE_AGENT);
}
__device__ __forceinline__ void store_ax(unsigned long long* p, unsigned long long v){
  __hip_atomic_store(p, v, __ATOMIC_RELAXED, __HIP_MEMORY_SCOPE_AGENT);
}
__device__ __forceinline__ void wait_vm0(){ asm volatile("s_waitcnt vmcnt(0)" ::: "memory"); }

// ---------------------------------------------------------------------------
// prep_a: combined weights (fp32): Wse=We[0:256]@Wei, Wre=We[256:512]@Wei (plain col),
//   WcmGI [4][1024] gate-interleaved (col' = hcol*4+g), bcmGI, bceGI interleaved.
//   Also zeroes barrier counters + Afin.
__global__ __launch_bounds__(256) void prep_a(
    const float* __restrict__ We, const float* __restrict__ Wei,
    const float* __restrict__ Wm, const float* __restrict__ Wmi,
    const float* __restrict__ bm, const float* __restrict__ bmi, const float* __restrict__ bmh,
    const float* __restrict__ be, const float* __restrict__ bei, const float* __restrict__ beh,
    float* __restrict__ Wse, float* __restrict__ Wre, float* __restrict__ WcmGI,
    float* __restrict__ bcmGI, float* __restrict__ bceGI,
    float* __restrict__ Afin, unsigned int* __restrict__ ectr, unsigned int* __restrict__ mctr){
  int bid = blockIdx.x, tid = threadIdx.x;
  if (bid < 2048){
    int idx = bid*256 + tid;
    int half = idx >> 18;
    int j = idx & 262143;
    int k = j >> 10, nn = j & 1023;
    const float* Wrow = We + (half*256 + k)*128;
    float s = 0.f;
    for (int d = 0; d < 128; ++d) s += Wrow[d] * Wei[d*1024 + nn];
    (half ? Wre : Wse)[k*1024 + nn] = s;
  } else if (bid < 2064){
    int idx = (bid-2048)*256 + tid;
    int d = idx >> 10, ci = idx & 1023;
    int col = (ci & 3)*256 + (ci >> 2);
    float s = 0.f;
    for (int j = 0; j < 128; ++j) s += Wm[d*128 + j] * Wmi[j*1024 + col];
    WcmGI[idx] = s;
  } else if (bid < 2068){
    int ci = (bid-2064)*256 + tid;
    int col = (ci & 3)*256 + (ci >> 2);
    float s = bmi[col] + bmh[col];
    for (int j = 0; j < 128; ++j) s += bm[j] * Wmi[j*1024 + col];
    bcmGI[ci] = s;
  } else if (bid < 2072){
    int ci = (bid-2068)*256 + tid;
    int col = (ci & 3)*256 + (ci >> 2);
    float s = bei[col] + beh[col];
    for (int j = 0; j < 128; ++j) s += be[j] * Wei[j*1024 + col];
    bceGI[ci] = s;
  } else if (bid == 2072){
    if (tid < 64) ectr[tid] = 0u;
    else if (tid < 96) mctr[tid-64] = 0u;
  } else {
    int idx = (bid-2073)*256 + tid;
    if (idx < NBATCH*NEDGE) Afin[idx] = 0.f;
  }
}

// ---------------------------------------------------------------------------
// prep_b packing.
__device__ __forceinline__ void pack_gi(const float* __restrict__ W,
                                        unsigned short* __restrict__ dst, int id){
  int lane = id & 63, kt = (id >> 6) & 7, tt = (id >> 9) & 1, w = (id >> 10) & 7, nb = id >> 13;
  int cl = lane & 15, q = lane >> 4;
  int gcol = (cl & 3)*256 + nb*64 + (w*2 + tt)*4 + (cl >> 2);
  int k0 = kt*32 + q*8;
  unsigned int wb[4];
  #pragma unroll
  for (int p = 0; p < 4; ++p){
    unsigned short a = f2bf(W[(k0+2*p  )*1024 + gcol]);
    unsigned short b = f2bf(W[(k0+2*p+1)*1024 + gcol]);
    wb[p] = (unsigned int)a | ((unsigned int)b << 16);
  }
  ((uint4*)dst)[id] = make_uint4(wb[0], wb[1], wb[2], wb[3]);
}

__device__ __forceinline__ void pack_one(const float* __restrict__ S,
                                         unsigned short* __restrict__ dst, int id, int n){
  int lane = id & 63, kt = (id >> 6) & 7;
  int k0 = kt*32 + ((lane >> 4) << 3);
  unsigned int wb[4];
  #pragma unroll
  for (int p = 0; p < 4; ++p){
    unsigned short a = f2bf(S[(k0+2*p  )*1024 + n]);
    unsigned short b = f2bf(S[(k0+2*p+1)*1024 + n]);
    wb[p] = (unsigned int)a | ((unsigned int)b << 16);
  }
  ((uint4*)dst)[id] = make_uint4(wb[0], wb[1], wb[2], wb[3]);
}

__global__ __launch_bounds__(256) void prep_b(
    const float* __restrict__ Wmh, const float* __restrict__ Weh,
    const float* __restrict__ Wse, const float* __restrict__ Wre,
    unsigned short* __restrict__ pWmh, unsigned short* __restrict__ pWeh,
    unsigned short* __restrict__ pWsr){
  int gid = blockIdx.x*256 + threadIdx.x;
  if (gid < 32768){
    pack_gi(Wmh, pWmh, gid);
  } else if (gid < 65536){
    pack_gi(Weh, pWeh, gid - 32768);
  } else {
    int id = gid - 65536;
    int ng = (id >> 9)*16 + (id & 15);
    const float* S = (ng < 1024) ? Wse : Wre;
    pack_one(S, pWsr, id, ng & 1023);
  }
}

// ---------------------------------------------------------------------------
// motion_lstm (persistent, register weights, relaxed-sc1 exchange):
// grid 128 = 32 m-tiles (10 seqs) x 4 n-slices. 512 thr = 8 waves.
__global__ __launch_bounds__(512, 2) void motion_lstm(
    const float* __restrict__ X, const float* __restrict__ WcmGI,
    const float* __restrict__ bcmGI, const unsigned short* __restrict__ pWmh,
    unsigned short* __restrict__ hm, unsigned short* __restrict__ mb,
    unsigned int* __restrict__ mctr){
  __shared__ __align__(16) unsigned short hst[16*RS];     // 8960 B
  __shared__ float dxs[10*252];
  __shared__ __align__(16) float sWc[4*256];
  __shared__ __align__(16) float sbc[256];
  __shared__ __align__(16) float scr[8*2*320];
  int tid = threadIdx.x, lane = tid & 63, w = tid >> 6;
  int l15 = lane & 15, quad = lane >> 4;
  int row16 = lane >> 2, h4 = lane & 3;
  int m = blockIdx.x & 31, n = blockIdx.x >> 5;
  int s0 = m*10;
  unsigned int* ctr = mctr + m;

  uint4 wreg[2][8];
  #pragma unroll
  for (int tt = 0; tt < 2; ++tt)
    #pragma unroll
    for (int kt = 0; kt < 8; ++kt)
      wreg[tt][kt] = ((const uint4*)pWmh)[(((n*8 + w)*2 + tt)*8 + kt)*64 + lane];

  uint4 z4 = make_uint4(0,0,0,0);
  for (int i = tid; i < 560; i += 512) ((uint4*)hst)[i] = z4;
  for (int i = tid; i < 1024; i += 512) sWc[i] = WcmGI[(i >> 8)*1024 + n*256 + (i & 255)];
  if (tid < 256) sbc[tid] = bcmGI[n*256 + tid];
  for (int i = tid; i < 2520; i += 512){
    int sl = i / 252; int r = i % 252; int t = r >> 2; int d = r & 3;
    const float* Xp = X + (((size_t)(s0 + sl)*64 + t)*4 + d);
    dxs[i] = Xp[4] - Xp[0];
  }
  __syncthreads();

  float ce[2] = {0.f, 0.f};
  int sl = row16 < 10 ? row16 : 9;

  for (int t = 0; t < TSTEPS; ++t){
    if (t > 0){
      if (tid == 0){
        unsigned int tgt = 4u*(unsigned)t;
        while (__hip_atomic_load(ctr, __ATOMIC_RELAXED, __HIP_MEMORY_SCOPE_AGENT) < tgt)
          __builtin_amdgcn_s_sleep(1);
      }
      __syncthreads();                                    // B1
      const unsigned long long* mbp = (const unsigned long long*)
          (mb + ((size_t)((t-1)&1)*32 + m)*16*256);
      unsigned long long pv[2]; int po[2] = {-1,-1};
      #pragma unroll
      for (int j = 0; j < 2; ++j){
        int i = tid + j*512;                              // 0..767: 3 slices x 256 ull
        if (i < 768){
          int which = i >> 8, jj = i & 255;
          int r = jj >> 4, c = jj & 15;
          int np = which + (which >= n ? 1 : 0);
          pv[j] = load_ax(&mbp[(size_t)r*64 + np*16 + c]);
          po[j] = r*RS + np*64 + c*4;
        }
      }
      #pragma unroll
      for (int j = 0; j < 2; ++j)
        if (po[j] >= 0) *(unsigned long long*)&hst[po[j]] = pv[j];
    }
    __syncthreads();                                      // B2

    f32x4 acc0 = {0.f,0.f,0.f,0.f}, acc1 = {0.f,0.f,0.f,0.f};
    #pragma unroll
    for (int kt = 0; kt < 8; ++kt){
      bf16x8 a = as_frag(*(const uint4*)&hst[l15*RS + kt*32 + quad*8]);
      acc0 = __builtin_amdgcn_mfma_f32_16x16x32_bf16(a, as_frag(wreg[0][kt]), acc0, 0, 0, 0);
      acc1 = __builtin_amdgcn_mfma_f32_16x16x32_bf16(a, as_frag(wreg[1][kt]), acc1, 0, 0, 0);
    }
    __syncthreads();                                      // B3 (hst reads done)

    int wb = w*640;
    #pragma unroll
    for (int r = 0; r < 4; ++r){
      scr[wb +       (quad*4 + r)*20 + l15] = acc0[r];
      scr[wb + 320 + (quad*4 + r)*20 + l15] = acc1[r];
    }
    #pragma unroll
    for (int tt = 0; tt < 2; ++tt){
      int tile = w*2 + tt;
      f32x4 v = *(const f32x4*)&scr[wb + tt*320 + row16*20 + h4*4];
      f32x4 bias = *(const f32x4*)&sbc[tile*16 + h4*4];
      float g0 = v[0] + bias[0], g1 = v[1] + bias[1], g2 = v[2] + bias[2], g3 = v[3] + bias[3];
      #pragma unroll
      for (int d = 0; d < 4; ++d){
        float dx = dxs[sl*252 + t*4 + d];
        f32x4 wv = *(const f32x4*)&sWc[d*256 + tile*16 + h4*4];
        g0 += dx*wv[0]; g1 += dx*wv[1]; g2 += dx*wv[2]; g3 += dx*wv[3];
      }
      float iv = sigmf(g0), fv = sigmf(g1), gv = tanh_f(g2), ov = sigmf(g3);
      float cc = fv*ce[tt] + iv*gv; ce[tt] = cc;
      hst[row16*RS + n*64 + tile*4 + h4] = f2bf(ov*tanh_f(cc));
    }
    __syncthreads();                                      // B4 (hst writes visible)

    unsigned long long* mbc = (unsigned long long*)
        (mb + ((size_t)(t&1)*32 + m)*16*256);
    if (tid < 256){
      int r = tid >> 4, c = tid & 15;
      unsigned long long v = *(const unsigned long long*)&hst[r*RS + n*64 + c*4];
      if (t < 62) store_ax(&mbc[(size_t)r*64 + n*16 + c], v);
      if (r < 10)
        *(unsigned long long*)&hm[(((size_t)(s0 + r)*63) + t)*256 + n*64 + c*4] = v;
    }
    wait_vm0();
    __syncthreads();                                      // B5 (all stores drained)
    if (t < 62 && tid == 0)
      __hip_atomic_fetch_add(ctr, 1u, __ATOMIC_RELAXED, __HIP_MEMORY_SCOPE_AGENT);
  }
}

// ---------------------------------------------------------------------------
// gsr_gemm: gsr = hm @ [Wse|Wre]  (M=20160, N=2048, K=256), bf16 out,
// gate-interleaved per half: col' = half*1024 + hcol*4 + gate. (verified R1/R2)
__global__ __launch_bounds__(256) void gsr_gemm(
    const unsigned short* __restrict__ hm, const unsigned short* __restrict__ pWsr,
    unsigned short* __restrict__ gsr){
  int tid = threadIdx.x, lane = tid & 63, wid = tid >> 6;
  int l15 = lane & 15, quad = lane >> 4;
  int bm = blockIdx.x % 315, bn = blockIdx.x / 315;
  int rowbase = bm*64 + (wid >> 1)*32;
  int ntbase  = bn*8  + (wid & 1)*4;
  f32x4 acc[2][4] = {};
  #pragma unroll
  for (int kt = 0; kt < 8; ++kt){
    bf16x8 af[2];
    #pragma unroll
    for (int mt = 0; mt < 2; ++mt){
      int row = rowbase + mt*16 + l15;
      af[mt] = as_frag(*(const uint4*)&hm[(size_t)row*256 + kt*32 + quad*8]);
    }
    #pragma unroll
    for (int nt = 0; nt < 4; ++nt){
      bf16x8 bfr = as_frag(*(const uint4*)&pWsr[(((size_t)(ntbase+nt)*8 + kt)*64 + lane)*8]);
      #pragma unroll
      for (int mt = 0; mt < 2; ++mt)
        acc[mt][nt] = __builtin_amdgcn_mfma_f32_16x16x32_bf16(af[mt], bfr, acc[mt][nt], 0, 0, 0);
    }
  }
  #pragma unroll
  for (int mt = 0; mt < 2; ++mt)
    #pragma unroll
    for (int nt = 0; nt < 4; ++nt){
      int col = (ntbase+nt)*16 + l15;
      int half = col >> 10, ch = col & 1023;
      int colp = (half << 10) | ((ch & 255)*4 + (ch >> 8));
      #pragma unroll
      for (int r = 0; r < 4; ++r){
        int row = rowbase + mt*16 + quad*4 + r;
        gsr[(size_t)row*2048 + colp] = f2bf(acc[mt][nt][r]);
      }
    }
}

// ---------------------------------------------------------------------------
// edge_lstm (persistent, relaxed-sc1 exchange): grid 256 = 16 b x 4 m x 4 n.
// 512 thr = 8 waves; weights register-resident; exchange via hb parity buffers.
__global__ __launch_bounds__(512, 2) void edge_lstm(
    const unsigned short* __restrict__ gsr, const float* __restrict__ bceGI,
    const unsigned short* __restrict__ pWeh, const float* __restrict__ Wf,
    unsigned short* __restrict__ hb, float* __restrict__ Afin,
    unsigned int* __restrict__ ectr){
  __shared__ __align__(16) unsigned short hst[96*RS];       // 53760 B
  __shared__ __align__(16) unsigned short gbuf[2*25*264];   // 26400 B
  __shared__ __align__(16) float scr[8*2*320];              // 20480 B
  __shared__ __align__(16) float sbce[256];
  __shared__ __align__(16) float sWf[64];
  int tid = threadIdx.x, lane = tid & 63, w = tid >> 6;
  int l15 = lane & 15, quad = lane >> 4;
  int row16 = lane >> 2, h4 = lane & 3;
  int bid = blockIdx.x;
  int n = bid >> 6, G = bid & 63, b = G >> 2, m = G & 3;
  int e0 = m*95;
  unsigned int* ctr = ectr + G;

  uint4 wreg[2][8];
  #pragma unroll
  for (int tt = 0; tt < 2; ++tt)
    #pragma unroll
    for (int kt = 0; kt < 8; ++kt)
      wreg[tt][kt] = ((const uint4*)pWeh)[(((n*8 + w)*2 + tt)*8 + kt)*64 + lane];

  if (tid < 256) sbce[tid] = bceGI[n*256 + tid];
  if (tid < 64)  sWf[tid]  = Wf[n*64 + tid];
  uint4 z4 = make_uint4(0,0,0,0);
  for (int i = tid; i < 3360; i += 512) ((uint4*)hst)[i] = z4;

  int srel[6], rrec[6];
  #pragma unroll
  for (int mt = 0; mt < 6; ++mt){
    int row = mt*16 + row16;
    int e = e0 + (row < 95 ? row : 94);
    int s = e / 19; int rr = e - s*19;
    srel[mt] = s - m*5;
    rrec[mt] = rr + (rr >= s ? 1 : 0);
  }

  // stage gather t=0 into gbuf[0]
  #pragma unroll
  for (int j = 0; j < 2; ++j){
    int i = tid + j*512;
    if (i < 800){
      int r = i >> 5, c = i & 31;
      int node = r < 5 ? m*5 + r : r - 5;
      int half = r < 5 ? 0 : 1024;
      uint4 v = *(const uint4*)&gsr[((size_t)(b*20 + node)*63)*2048 + half + n*256 + c*8];
      *(uint4*)&gbuf[r*264 + c*8] = v;
    }
  }
  __syncthreads();

  float ce[2][6]; float epi[6];
  #pragma unroll
  for (int mt = 0; mt < 6; ++mt){ ce[0][mt] = 0.f; ce[1][mt] = 0.f; epi[mt] = 0.f; }

  for (int t = 0; t < TSTEPS; ++t){
    if (t > 0){
      if (tid == 0){
        unsigned int tgt = 4u*(unsigned)t;
        while (__hip_atomic_load(ctr, __ATOMIC_RELAXED, __HIP_MEMORY_SCOPE_AGENT) < tgt)
          __builtin_amdgcn_s_sleep(1);
      }
      __syncthreads();                                    // B1
      const unsigned long long* hbp = (const unsigned long long*)
          (hb + (((size_t)((t-1)&1)*16 + b)*4 + m)*96*256);
      unsigned long long pv[9]; int po[9];
      #pragma unroll
      for (int j = 0; j < 9; ++j){
        int i = tid + j*512;                              // 0..4607: 3 slices x 1536 ull
        int which = i / 1536, jj = i - which*1536;
        int r = jj >> 4, c = jj & 15;
        int np = which + (which >= n ? 1 : 0);
        pv[j] = load_ax(&hbp[(size_t)r*64 + np*16 + c]);
        po[j] = r*RS + np*64 + c*4;
      }
      #pragma unroll
      for (int j = 0; j < 9; ++j)
        *(unsigned long long*)&hst[po[j]] = pv[j];
    }
    // gsr prefetch for t+1 into the other gbuf half
    if (t+1 < TSTEPS){
      #pragma unroll
      for (int j = 0; j < 2; ++j){
        int i = tid + j*512;
        if (i < 800){
          int r = i >> 5, c = i & 31;
          int node = r < 5 ? m*5 + r : r - 5;
          int half = r < 5 ? 0 : 1024;
          uint4 v = *(const uint4*)&gsr[(((size_t)(b*20 + node)*63) + (t+1))*2048 + half + n*256 + c*8];
          *(uint4*)&gbuf[((t+1)&1)*6600 + r*264 + c*8] = v;
        }
      }
    }
    __syncthreads();                                      // B2

    f32x4 acc[2][6];
    #pragma unroll
    for (int mt = 0; mt < 6; ++mt){ acc[0][mt] = (f32x4){0,0,0,0}; acc[1][mt] = (f32x4){0,0,0,0}; }
    #pragma unroll
    for (int kt = 0; kt < 8; ++kt){
      bf16x8 a[6];
      #pragma unroll
      for (int mt = 0; mt < 6; ++mt)
        a[mt] = as_frag(*(const uint4*)&hst[(mt*16 + l15)*RS + kt*32 + quad*8]);
      #pragma unroll
      for (int mt = 0; mt < 6; ++mt){
        acc[0][mt] = __builtin_amdgcn_mfma_f32_16x16x32_bf16(a[mt], as_frag(wreg[0][kt]), acc[0][mt], 0, 0, 0);
        acc[1][mt] = __builtin_amdgcn_mfma_f32_16x16x32_bf16(a[mt], as_frag(wreg[1][kt]), acc[1][mt], 0, 0, 0);
      }
    }
    __syncthreads();                                      // B3 (hst reads done)

    int bufo = (t & 1)*6600;
    int wb = w*640;
    #pragma unroll
    for (int mt = 0; mt < 6; ++mt){
      #pragma unroll
      for (int r = 0; r < 4; ++r){
        scr[wb +       (quad*4 + r)*20 + l15] = acc[0][mt][r];
        scr[wb + 320 + (quad*4 + r)*20 + l15] = acc[1][mt][r];
      }
      #pragma unroll
      for (int tt = 0; tt < 2; ++tt){
        int tile = w*2 + tt;
        int tb = tile*16 + h4*4;
        f32x4 v = *(const f32x4*)&scr[wb + tt*320 + row16*20 + h4*4];
        uint2 gs = *(const uint2*)&gbuf[bufo + srel[mt]*264 + tb];
        uint2 gr = *(const uint2*)&gbuf[bufo + (5 + rrec[mt])*264 + tb];
        f32x4 bias = *(const f32x4*)&sbce[tb];
        float g0 = v[0] + bias[0] + bf2f((unsigned short)(gs.x & 0xffff)) + bf2f((unsigned short)(gr.x & 0xffff));
        float g1 = v[1] + bias[1] + bf2f((unsigned short)(gs.x >> 16))    + bf2f((unsigned short)(gr.x >> 16));
        float g2 = v[2] + bias[2] + bf2f((unsigned short)(gs.y & 0xffff)) + bf2f((unsigned short)(gr.y & 0xffff));
        float g3 = v[3] + bias[3] + bf2f((unsigned short)(gs.y >> 16))    + bf2f((unsigned short)(gr.y >> 16));
        float iv = sigmf(g0), fv = sigmf(g1), gv = tanh_f(g2), ov = sigmf(g3);
        float cc = fv*ce[tt][mt] + iv*gv; ce[tt][mt] = cc;
        float h = ov*tanh_f(cc);
        int row = mt*16 + row16;
        if (t < 62){
          hst[row*RS + n*64 + tile*4 + h4] = f2bf(h);
        } else {
          epi[mt] += h * sWf[tile*4 + h4];
        }
      }
    }
    if (t < 62){
      __syncthreads();                                    // B4 (hst writes visible)
      unsigned long long* hbc = (unsigned long long*)
          (hb + (((size_t)(t&1)*16 + b)*4 + m)*96*256);
      #pragma unroll
      for (int j = 0; j < 3; ++j){
        int i = tid + j*512;                              // 0..1535
        int r = i >> 4, c = i & 15;
        unsigned long long v = *(const unsigned long long*)&hst[r*RS + n*64 + c*4];
        store_ax(&hbc[(size_t)r*64 + n*16 + c], v);
      }
      wait_vm0();
      __syncthreads();                                    // B5
      if (tid == 0)
        __hip_atomic_fetch_add(ctr, 1u, __ATOMIC_RELAXED, __HIP_MEMORY_SCOPE_AGENT);
    }
  }
  // epilogue: per-edge partial dot with Wf -> atomic accumulate
  #pragma unroll
  for (int mt = 0; mt < 6; ++mt){
    float v = epi[mt];
    v += __shfl_xor(v, 1);
    v += __shfl_xor(v, 2);
    int row = mt*16 + row16;
    if (h4 == 0 && row < 95)
      atomicAdd(&Afin[b*380 + e0 + row], v);
  }
}

// ---------------------------------------------------------------------------
// finalize: out[b,i,j] = (i==j) ? 0 : 0.5*(sig(A[e1]+bf) + sig(A[e2]+bf))
__global__ __launch_bounds__(256) void finalize(const float* __restrict__ Afin,
                                                const float* __restrict__ bfp,
                                                float* __restrict__ out){
  int idx = blockIdx.x*256 + threadIdx.x;
  if (idx >= 16*400) return;
  int b = idx / 400; int ij = idx % 400; int i = ij / 20; int j = ij % 20;
  float v = 0.f;
  if (i != j){
    int e1 = i*19 + j - (j > i ? 1 : 0);
    int e2 = j*19 + i - (i > j ? 1 : 0);
    float bf = bfp[0];
    v = 0.5f*(sigmf(Afin[b*380 + e1] + bf) + sigmf(Afin[b*380 + e2] + bf));
  }
  out[idx] = v;
}

// ---------------------------------------------------------------------------
extern "C" void kernel_launch(void* const* d_in, const int* in_sizes, int n_in,
                              void* d_out, int out_size, void* d_ws, size_t ws_size,
                              hipStream_t stream){
  (void)in_sizes; (void)n_in; (void)out_size; (void)ws_size;
  const float* X   = (const float*)d_in[0];
  const float* Wm  = (const float*)d_in[3];
  const float* bm  = (const float*)d_in[4];
  const float* Wmi = (const float*)d_in[5];
  const float* bmi = (const float*)d_in[6];
  const float* Wmh = (const float*)d_in[7];
  const float* bmh = (const float*)d_in[8];
  const float* We  = (const float*)d_in[9];
  const float* be  = (const float*)d_in[10];
  const float* Wei = (const float*)d_in[11];
  const float* bei = (const float*)d_in[12];
  const float* Weh = (const float*)d_in[13];
  const float* beh = (const float*)d_in[14];
  const float* Wf  = (const float*)d_in[15];
  const float* bfp = (const float*)d_in[16];

  char* ws = (char*)d_ws;
  float* Wse   = (float*)(ws + 0);                          // 1 MB
  float* Wre   = (float*)(ws + 1048576);                    // 1 MB
  float* WcmGI = (float*)(ws + 2097152);                    // 16 KB
  float* bcmGI = (float*)(ws + 2113536);                    // 4 KB
  float* bceGI = (float*)(ws + 2117632);                    // 4 KB
  unsigned short* pWmh = (unsigned short*)(ws + 2121728);   // 512 KB
  unsigned short* pWeh = (unsigned short*)(ws + 2646016);   // 512 KB
  unsigned short* pWsr = (unsigned short*)(ws + 3170304);   // 1 MB
  unsigned short* hm   = (unsigned short*)(ws + 4218880);   // 10.3 MB
  unsigned short* gsr  = (unsigned short*)(ws + 14540800);  // 82.6 MB
  unsigned short* hb   = (unsigned short*)(ws + 97116160);  // 6.3 MB (edge exchange)
  unsigned short* mb   = hb;                                // aliased: disjoint lifetime
  float* Afin          = (float*)(ws + 103407616);          // 24 KB
  unsigned int* ectr   = (unsigned int*)(ws + 103432192);   // 256 B
  unsigned int* mctr   = (unsigned int*)(ws + 103432448);   // 128 B
  float* out = (float*)d_out;

  hipLaunchKernelGGL(prep_a, dim3(2097), dim3(256), 0, stream,
                     We, Wei, Wm, Wmi, bm, bmi, bmh, be, bei, beh,
                     Wse, Wre, WcmGI, bcmGI, bceGI, Afin, ectr, mctr);
  hipLaunchKernelGGL(prep_b, dim3(512), dim3(256), 0, stream,
                     Wmh, Weh, Wse, Wre, pWmh, pWeh, pWsr);
  {
    void* margs[] = {(void*)&X, (void*)&WcmGI, (void*)&bcmGI, (void*)&pWmh,
                     (void*)&hm, (void*)&mb, (void*)&mctr};
    hipLaunchCooperativeKernel(reinterpret_cast<void*>(motion_lstm),
                               dim3(128), dim3(512), margs, 0, stream);
  }
  hipLaunchKernelGGL(gsr_gemm, dim3(315*16), dim3(256), 0, stream,
                     hm, pWsr, gsr);
  {
    void* eargs[] = {(void*)&gsr, (void*)&bceGI, (void*)&pWeh, (void*)&Wf,
                     (void*)&hb, (void*)&Afin, (void*)&ectr};
    hipLaunchCooperativeKernel(reinterpret_cast<void*>(edge_lstm),
                               dim3(256), dim3(512), eargs, 0, stream);
  }
  hipLaunchKernelGGL(finalize, dim3(25), dim3(256), 0, stream,
                     Afin, bfp, out);
}